// Round 1
// baseline (206.107 us; speedup 1.0000x reference)
//
#include <hip/hip_runtime.h>
#include <math.h>

#define BDIM 64
#define SDIM 2048
#define DDIM 256

// Kernel 1: partial masked max/sum over an S-chunk.
// Block = 256 threads = 4 waves. Lane owns a float4 d-slice (64*4 = 256 = D).
// Wave w handles rows s = w, w+4, ... within the chunk -> mask test is
// wave-uniform; masked-out rows are never fetched from HBM.
__global__ __launch_bounds__(256) void fe_partial(const float* __restrict__ feats,
                                                  const float* __restrict__ mask,
                                                  float* __restrict__ ws,
                                                  int rows_per_chunk) {
    const int b    = blockIdx.x;
    const int c    = blockIdx.y;
    const int tid  = threadIdx.x;
    const int wave = tid >> 6;
    const int lane = tid & 63;
    const int d4   = lane << 2;

    const int s0 = c * rows_per_chunk;
    const float* __restrict__ fb = feats + ((size_t)b * SDIM + (size_t)s0) * DDIM;
    const float* __restrict__ mb = mask + (size_t)b * SDIM + s0;

    float4 mx = make_float4(-INFINITY, -INFINITY, -INFINITY, -INFINITY);
    float4 sm = make_float4(0.f, 0.f, 0.f, 0.f);

    for (int s = wave; s < rows_per_chunk; s += 4) {
        const float m = mb[s];  // broadcast load, L1/L2-served
        if (m > 0.0f) {         // wave-uniform branch; skips the 1 KiB row fetch
            const float4 v = *(const float4*)(fb + (size_t)s * DDIM + d4);
            mx.x = fmaxf(mx.x, v.x); mx.y = fmaxf(mx.y, v.y);
            mx.z = fmaxf(mx.z, v.z); mx.w = fmaxf(mx.w, v.w);
            sm.x += v.x; sm.y += v.y; sm.z += v.z; sm.w += v.w;
        }
    }

    __shared__ float4 s_mx[256];
    __shared__ float4 s_sm[256];
    s_mx[tid] = mx;
    s_sm[tid] = sm;
    __syncthreads();

    if (wave == 0) {
#pragma unroll
        for (int w = 1; w < 4; ++w) {
            const float4 a = s_mx[w * 64 + lane];
            const float4 s = s_sm[w * 64 + lane];
            mx.x = fmaxf(mx.x, a.x); mx.y = fmaxf(mx.y, a.y);
            mx.z = fmaxf(mx.z, a.z); mx.w = fmaxf(mx.w, a.w);
            sm.x += s.x; sm.y += s.y; sm.z += s.z; sm.w += s.w;
        }
        float* __restrict__ wout = ws + ((size_t)b * gridDim.y + c) * (2 * DDIM);
        *(float4*)(wout + d4)        = mx;
        *(float4*)(wout + DDIM + d4) = sm;
    }
}

// Kernel 2: combine C chunk-partials per b; compute length = sum(mask[b,:]);
// out[b][0:256] = max, out[b][256:512] = sum / length.
__global__ __launch_bounds__(256) void fe_combine(const float* __restrict__ ws,
                                                  const float* __restrict__ mask,
                                                  float* __restrict__ out,
                                                  int C) {
    const int b    = blockIdx.x;
    const int tid  = threadIdx.x;
    const int wave = tid >> 6;
    const int lane = tid & 63;

    // --- length = sum over S of mask[b, s] ---
    float part = 0.f;
    const float* __restrict__ mb = mask + (size_t)b * SDIM;
    for (int s = tid; s < SDIM; s += 256) part += mb[s];
#pragma unroll
    for (int off = 32; off > 0; off >>= 1) part += __shfl_down(part, off, 64);

    __shared__ float wsum[4];
    if (lane == 0) wsum[wave] = part;
    __syncthreads();
    const float length = wsum[0] + wsum[1] + wsum[2] + wsum[3];

    // --- combine partials: thread tid owns column d = tid ---
    float mx = -INFINITY;
    float sm = 0.f;
    for (int c = 0; c < C; ++c) {
        const float* __restrict__ w = ws + ((size_t)b * C + c) * (2 * DDIM);
        mx = fmaxf(mx, w[tid]);
        sm += w[DDIM + tid];
    }

    float* __restrict__ ob = out + (size_t)b * (2 * DDIM);
    ob[tid]        = mx;
    ob[DDIM + tid] = sm / length;
}

extern "C" void kernel_launch(void* const* d_in, const int* in_sizes, int n_in,
                              void* d_out, int out_size, void* d_ws, size_t ws_size,
                              hipStream_t stream) {
    const float* feats = (const float*)d_in[0];
    const float* mask  = (const float*)d_in[1];
    float* out         = (float*)d_out;
    float* ws          = (float*)d_ws;

    // Pick chunk count to fit workspace: need B * C * 2*D floats.
    int C = 16;
    while (C > 1 && (size_t)BDIM * C * 2 * DDIM * sizeof(float) > ws_size) C >>= 1;

    dim3 grid1(BDIM, C);
    fe_partial<<<grid1, 256, 0, stream>>>(feats, mask, ws, SDIM / C);
    fe_combine<<<BDIM, 256, 0, stream>>>(ws, mask, out, C);
}

// Round 2
// 186.457 us; speedup vs baseline: 1.1054x; 1.1054x over previous
//
#include <hip/hip_runtime.h>
#include <math.h>

#define BDIM 64
#define SDIM 2048
#define DDIM 256
#define CHUNKS 32
#define RPC (SDIM / CHUNKS)  // 64 rows per chunk

// ws layout: [0, 64): lengths (float), one per batch row
//            [64, 64 + B*CHUNKS*2*D): per-(b,chunk) partials (max[256] | sum[256])

// Kernel 0: lengths[b] = sum(mask[b, :]).  64 blocks x 256 threads.
__global__ __launch_bounds__(256) void fe_lengths(const float* __restrict__ mask,
                                                  float* __restrict__ ws_len) {
    const int b   = blockIdx.x;
    const int tid = threadIdx.x;
    const int wave = tid >> 6, lane = tid & 63;
    const float4* __restrict__ mb = (const float4*)(mask + (size_t)b * SDIM);
    // 2048 floats = 512 float4; each thread reads 2
    const float4 a = mb[tid];
    const float4 c = mb[tid + 256];
    float part = a.x + a.y + a.z + a.w + c.x + c.y + c.z + c.w;
#pragma unroll
    for (int off = 32; off > 0; off >>= 1) part += __shfl_down(part, off, 64);
    __shared__ float wsum[4];
    if (lane == 0) wsum[wave] = part;
    __syncthreads();
    if (tid == 0) ws_len[b] = wsum[0] + wsum[1] + wsum[2] + wsum[3];
}

// Kernel 1: partial max/sum over rows [c*RPC, c*RPC + active) where
// active = clamp(L - c*RPC, 0, RPC).  No per-row mask dependency: trip count
// known at loop entry, unroll x4 -> 4 KiB in flight per wave.
__global__ __launch_bounds__(256) void fe_partial(const float* __restrict__ feats,
                                                  const float* __restrict__ ws_len,
                                                  float* __restrict__ partials) {
    const int b    = blockIdx.x;
    const int c    = blockIdx.y;
    const int tid  = threadIdx.x;
    const int wave = tid >> 6;
    const int lane = tid & 63;
    const int d4   = lane << 2;   // lane owns float4 at column 4*lane

    const int L  = (int)ws_len[b];
    const int s0 = c * RPC;
    int active = L - s0;
    active = active < 0 ? 0 : (active > RPC ? RPC : active);

    // contiguous per-wave row range
    const int per = (active + 3) >> 2;
    int sb = wave * per; if (sb > active) sb = active;
    int se = sb + per;   if (se > active) se = active;

    const float* __restrict__ fb = feats + ((size_t)b * SDIM + s0) * DDIM + d4;

    float4 mx = make_float4(-INFINITY, -INFINITY, -INFINITY, -INFINITY);
    float4 sm = make_float4(0.f, 0.f, 0.f, 0.f);

    int s = sb;
    for (; s + 4 <= se; s += 4) {
        const float4 v0 = *(const float4*)(fb + (size_t)(s + 0) * DDIM);
        const float4 v1 = *(const float4*)(fb + (size_t)(s + 1) * DDIM);
        const float4 v2 = *(const float4*)(fb + (size_t)(s + 2) * DDIM);
        const float4 v3 = *(const float4*)(fb + (size_t)(s + 3) * DDIM);
        mx.x = fmaxf(fmaxf(fmaxf(mx.x, v0.x), fmaxf(v1.x, v2.x)), v3.x);
        mx.y = fmaxf(fmaxf(fmaxf(mx.y, v0.y), fmaxf(v1.y, v2.y)), v3.y);
        mx.z = fmaxf(fmaxf(fmaxf(mx.z, v0.z), fmaxf(v1.z, v2.z)), v3.z);
        mx.w = fmaxf(fmaxf(fmaxf(mx.w, v0.w), fmaxf(v1.w, v2.w)), v3.w);
        sm.x += v0.x + v1.x + v2.x + v3.x;
        sm.y += v0.y + v1.y + v2.y + v3.y;
        sm.z += v0.z + v1.z + v2.z + v3.z;
        sm.w += v0.w + v1.w + v2.w + v3.w;
    }
    for (; s < se; ++s) {
        const float4 v = *(const float4*)(fb + (size_t)s * DDIM);
        mx.x = fmaxf(mx.x, v.x); mx.y = fmaxf(mx.y, v.y);
        mx.z = fmaxf(mx.z, v.z); mx.w = fmaxf(mx.w, v.w);
        sm.x += v.x; sm.y += v.y; sm.z += v.z; sm.w += v.w;
    }

    __shared__ float4 s_mx[256];
    __shared__ float4 s_sm[256];
    s_mx[tid] = mx;
    s_sm[tid] = sm;
    __syncthreads();

    if (wave == 0) {
#pragma unroll
        for (int w = 1; w < 4; ++w) {
            const float4 a = s_mx[w * 64 + lane];
            const float4 t = s_sm[w * 64 + lane];
            mx.x = fmaxf(mx.x, a.x); mx.y = fmaxf(mx.y, a.y);
            mx.z = fmaxf(mx.z, a.z); mx.w = fmaxf(mx.w, a.w);
            sm.x += t.x; sm.y += t.y; sm.z += t.z; sm.w += t.w;
        }
        float* __restrict__ wout = partials + ((size_t)b * CHUNKS + c) * (2 * DDIM);
        *(float4*)(wout + d4)        = mx;
        *(float4*)(wout + DDIM + d4) = sm;
    }
}

// Kernel 2: reduce CHUNKS partials per (b, d); out[b] = [max | sum/L].
__global__ __launch_bounds__(256) void fe_combine(const float* __restrict__ partials,
                                                  const float* __restrict__ ws_len,
                                                  float* __restrict__ out) {
    const int b   = blockIdx.x;
    const int tid = threadIdx.x;
    const float L = ws_len[b];

    float mx = -INFINITY;
    float sm = 0.f;
    const float* __restrict__ base = partials + (size_t)b * CHUNKS * (2 * DDIM);
#pragma unroll 8
    for (int c = 0; c < CHUNKS; ++c) {
        mx = fmaxf(mx, base[(size_t)c * (2 * DDIM) + tid]);
        sm += base[(size_t)c * (2 * DDIM) + DDIM + tid];
    }

    float* __restrict__ ob = out + (size_t)b * (2 * DDIM);
    ob[tid]        = mx;
    ob[DDIM + tid] = sm / L;
}

extern "C" void kernel_launch(void* const* d_in, const int* in_sizes, int n_in,
                              void* d_out, int out_size, void* d_ws, size_t ws_size,
                              hipStream_t stream) {
    const float* feats = (const float*)d_in[0];
    const float* mask  = (const float*)d_in[1];
    float* out         = (float*)d_out;
    float* ws_len      = (float*)d_ws;
    float* partials    = ws_len + BDIM;  // 256 B offset, 16B-aligned

    fe_lengths<<<BDIM, 256, 0, stream>>>(mask, ws_len);
    dim3 grid1(BDIM, CHUNKS);
    fe_partial<<<grid1, 256, 0, stream>>>(feats, ws_len, partials);
    fe_combine<<<BDIM, 256, 0, stream>>>(partials, ws_len, out);
}

// Round 3
// 185.149 us; speedup vs baseline: 1.1132x; 1.0071x over previous
//
#include <hip/hip_runtime.h>
#include <math.h>

#define BDIM 64
#define SDIM 2048
#define DDIM 256
#define CHUNKS 32
#define RPC (SDIM / CHUNKS)  // 64 rows per chunk

// ws layout: B*CHUNKS*2*D floats of per-(b,chunk) partials (max[256] | sum[256])

// Kernel 1: partial max/sum over rows [s0, s0 + active).
// Prefix-mask property: active rows in this 64-row window = sum(mask[b, s0:s0+64]).
// Only 64 floats read -> no separate lengths kernel, no cross-kernel dependency.
__global__ __launch_bounds__(256) void fe_partial(const float* __restrict__ feats,
                                                  const float* __restrict__ mask,
                                                  float* __restrict__ partials) {
    const int b    = blockIdx.x;
    const int c    = blockIdx.y;
    const int tid  = threadIdx.x;
    const int wave = tid >> 6;
    const int lane = tid & 63;
    const int d4   = lane << 2;   // lane owns float4 at column 4*lane

    const int s0 = c * RPC;

    __shared__ float s_active;
    if (wave == 0) {
        float m = mask[(size_t)b * SDIM + s0 + lane];  // 64 floats, coalesced
#pragma unroll
        for (int off = 32; off > 0; off >>= 1) m += __shfl_down(m, off, 64);
        if (lane == 0) s_active = m;
    }
    __syncthreads();
    const int active = (int)s_active;   // rows to process in this window

    // contiguous per-wave row range
    const int per = (active + 3) >> 2;
    int sb = wave * per; if (sb > active) sb = active;
    int se = sb + per;   if (se > active) se = active;

    const float* __restrict__ fb = feats + ((size_t)b * SDIM + s0) * DDIM + d4;

    float4 mx = make_float4(-INFINITY, -INFINITY, -INFINITY, -INFINITY);
    float4 sm = make_float4(0.f, 0.f, 0.f, 0.f);

    int s = sb;
    for (; s + 4 <= se; s += 4) {
        const float4 v0 = *(const float4*)(fb + (size_t)(s + 0) * DDIM);
        const float4 v1 = *(const float4*)(fb + (size_t)(s + 1) * DDIM);
        const float4 v2 = *(const float4*)(fb + (size_t)(s + 2) * DDIM);
        const float4 v3 = *(const float4*)(fb + (size_t)(s + 3) * DDIM);
        mx.x = fmaxf(fmaxf(fmaxf(mx.x, v0.x), fmaxf(v1.x, v2.x)), v3.x);
        mx.y = fmaxf(fmaxf(fmaxf(mx.y, v0.y), fmaxf(v1.y, v2.y)), v3.y);
        mx.z = fmaxf(fmaxf(fmaxf(mx.z, v0.z), fmaxf(v1.z, v2.z)), v3.z);
        mx.w = fmaxf(fmaxf(fmaxf(mx.w, v0.w), fmaxf(v1.w, v2.w)), v3.w);
        sm.x += v0.x + v1.x + v2.x + v3.x;
        sm.y += v0.y + v1.y + v2.y + v3.y;
        sm.z += v0.z + v1.z + v2.z + v3.z;
        sm.w += v0.w + v1.w + v2.w + v3.w;
    }
    for (; s < se; ++s) {
        const float4 v = *(const float4*)(fb + (size_t)s * DDIM);
        mx.x = fmaxf(mx.x, v.x); mx.y = fmaxf(mx.y, v.y);
        mx.z = fmaxf(mx.z, v.z); mx.w = fmaxf(mx.w, v.w);
        sm.x += v.x; sm.y += v.y; sm.z += v.z; sm.w += v.w;
    }

    __shared__ float4 s_mx[256];
    __shared__ float4 s_sm[256];
    s_mx[tid] = mx;
    s_sm[tid] = sm;
    __syncthreads();

    if (wave == 0) {
#pragma unroll
        for (int w = 1; w < 4; ++w) {
            const float4 a = s_mx[w * 64 + lane];
            const float4 t = s_sm[w * 64 + lane];
            mx.x = fmaxf(mx.x, a.x); mx.y = fmaxf(mx.y, a.y);
            mx.z = fmaxf(mx.z, a.z); mx.w = fmaxf(mx.w, a.w);
            sm.x += t.x; sm.y += t.y; sm.z += t.z; sm.w += t.w;
        }
        float* __restrict__ wout = partials + ((size_t)b * CHUNKS + c) * (2 * DDIM);
        *(float4*)(wout + d4)        = mx;
        *(float4*)(wout + DDIM + d4) = sm;
    }
}

// Kernel 2: reduce CHUNKS partials per (b, d); compute L = sum(mask[b,:]) in-kernel;
// out[b] = [max | sum/L].
__global__ __launch_bounds__(256) void fe_combine(const float* __restrict__ partials,
                                                  const float* __restrict__ mask,
                                                  float* __restrict__ out) {
    const int b    = blockIdx.x;
    const int tid  = threadIdx.x;
    const int wave = tid >> 6;
    const int lane = tid & 63;

    // L = sum over S of mask[b, :]  (8 KB, L2-hot from fe_partial's touches)
    const float4* __restrict__ mb = (const float4*)(mask + (size_t)b * SDIM);
    const float4 a = mb[tid];
    const float4 c4 = mb[tid + 256];
    float part = a.x + a.y + a.z + a.w + c4.x + c4.y + c4.z + c4.w;
#pragma unroll
    for (int off = 32; off > 0; off >>= 1) part += __shfl_down(part, off, 64);
    __shared__ float wsum[4];
    if (lane == 0) wsum[wave] = part;
    __syncthreads();
    const float L = wsum[0] + wsum[1] + wsum[2] + wsum[3];

    // combine partials: thread tid owns column d = tid
    float mx = -INFINITY;
    float sm = 0.f;
    const float* __restrict__ base = partials + (size_t)b * CHUNKS * (2 * DDIM);
#pragma unroll 8
    for (int c = 0; c < CHUNKS; ++c) {
        mx = fmaxf(mx, base[(size_t)c * (2 * DDIM) + tid]);
        sm += base[(size_t)c * (2 * DDIM) + DDIM + tid];
    }

    float* __restrict__ ob = out + (size_t)b * (2 * DDIM);
    ob[tid]        = mx;
    ob[DDIM + tid] = sm / L;
}

extern "C" void kernel_launch(void* const* d_in, const int* in_sizes, int n_in,
                              void* d_out, int out_size, void* d_ws, size_t ws_size,
                              hipStream_t stream) {
    const float* feats = (const float*)d_in[0];
    const float* mask  = (const float*)d_in[1];
    float* out         = (float*)d_out;
    float* partials    = (float*)d_ws;

    dim3 grid1(BDIM, CHUNKS);
    fe_partial<<<grid1, 256, 0, stream>>>(feats, mask, partials);
    fe_combine<<<BDIM, 256, 0, stream>>>(partials, mask, out);
}